// Round 1
// 415.421 us; speedup vs baseline: 1.0134x; 1.0134x over previous
//
#include <hip/hip_runtime.h>
#include <hip/hip_bf16.h>

#define N_IN 5000
#define K_SEL 50
#define B_ROWS 16384
#define OUT_D 30
#define RPB 32                 // rows per block
#define GRID (B_ROWS / RPB)    // 512 blocks -> 2 blocks/CU, 8 waves/CU

// ---------------------------------------------------------------------------
// Fused kernel, occupancy-doubled: 512 blocks x 256 threads, 32 rows/block.
//
// Rationale (R1): rocprof showed the fused kernel at < 200 us while the
// 421 us bench figure includes two ~200 us harness poison-fills; marginal
// kernel time ~20 us, dominated by the latency-exposed scattered x-gather
// at 1 block/CU (1 wave/SIMD -> nothing to issue during ~900cy HBM misses).
// Halving rows/block and doubling the grid gives 2 resident blocks/CU
// (8 waves/CU): block B's top-k/compute overlaps block A's gather stalls.
//
// Phase A (per-block redundant top-k): unchanged logic. Every block reads
// the 5000 logits (L2-resident after first touch per XCD) and binary-
// searches on monotonic-mapped uint keys (20/thread) with early exit at
// count(>=mid)==K. Distinct inputs -> deterministic selected SET; block-
// internal order (LDS tickets) only needs block-internal consistency.
// Block 0 writes the k-hot mask.
//
// Phase B (gather): W1 rows for selected columns -> LDS (coalesced 128B);
// x gather with 8 threads/row, 7 fully-unrolled loads -> registers -> LDS
// (one HBM latency per thread, not 7 round trips).
//
// Phase C (MLP): j-partitioned across 8 chunks (c = tid>>5); h1/h2 through
// padded LDS (strides 51/33/17 -> conflict-free); float4 epilogue.
// ---------------------------------------------------------------------------
__global__ __launch_bounds__(256, 2) void fused_gated_mlp_kernel(
    const float* __restrict__ x,
    const float* __restrict__ logits,
    const float* __restrict__ W1,
    const float* __restrict__ b1,
    const float* __restrict__ W2,
    const float* __restrict__ b2,
    const float* __restrict__ W3,
    const float* __restrict__ b3,
    float* __restrict__ out,
    float* __restrict__ mask)
{
    __shared__ float xs[RPB * 51];      // gathered gated inputs (stride 51)
    __shared__ float h1s[RPB * 33];     // relu(L1) (stride 33)
    __shared__ float h2s[RPB * 17];     // relu(L2) (stride 17)
    __shared__ float sW1[K_SEL * 32];
    __shared__ float sW2[32 * 16];
    __shared__ float sW3[16 * OUT_D];
    __shared__ float sb1[32];
    __shared__ float sb2[16];
    __shared__ float sb3[OUT_D];
    __shared__ int   sidx[K_SEL];
    __shared__ unsigned int s_cnt[36];
    __shared__ int s_tick, s_sel;

    const int tid  = threadIdx.x;
    const int lane = tid & 63;

    if (tid < 36) s_cnt[tid] = 0u;
    if (tid == 40) s_tick = 0;
    if (tid == 41) s_sel = 0;

    // --- idx-independent weight staging: loads overlap the top-k phase ---
    for (int e = tid; e < 32 * 16; e += 256) sW2[e] = W2[e];
    for (int e = tid; e < 16 * OUT_D; e += 256) sW3[e] = W3[e];
    if (tid < 32) sb1[tid] = b1[tid];
    if (tid < 16) sb2[tid] = b2[tid];
    if (tid < OUT_D) sb3[tid] = b3[tid];

    // --- Phase A: top-k. 20 keys/thread, monotonic uint map ---
    unsigned int key[20];
#pragma unroll
    for (int j = 0; j < 20; j++) {
        int i = tid + j * 256;
        if (i < N_IN) {
            unsigned int b = __float_as_uint(logits[i]);
            key[j] = (b & 0x80000000u) ? ~b : (b | 0x80000000u);
        } else {
            key[j] = 0u;
        }
    }
    __syncthreads();

    unsigned int lo = 0u, hi = 0xFFFFFFFFu;
    bool exact = false;
    unsigned int T = 0;
    for (int iter = 0; iter < 32; iter++) {
        if (lo >= hi) break;                         // uniform
        unsigned int mid = lo + ((hi - lo) >> 1) + 1u;
        unsigned int c = 0;
#pragma unroll
        for (int j = 0; j < 20; j++) c += (key[j] >= mid) ? 1u : 0u;
#pragma unroll
        for (int off = 32; off > 0; off >>= 1) c += __shfl_down(c, off, 64);
        if (lane == 0) atomicAdd(&s_cnt[iter], c);
        __syncthreads();
        unsigned int cnt = s_cnt[iter];
        if (cnt == (unsigned)K_SEL) { T = mid; exact = true; break; }  // uniform
        if (cnt > (unsigned)K_SEL) lo = mid; else hi = mid - 1u;
    }

    const bool write_mask = (blockIdx.x == 0);
    if (exact) {
        // Selection set is exactly {key >= T}: deterministic.
#pragma unroll
        for (int j = 0; j < 20; j++) {
            int i = tid + j * 256;
            if (i >= N_IN) continue;
            bool sel = (key[j] >= T);
            if (sel) { int s = atomicAdd(&s_sel, 1); sidx[s] = i; }
            if (write_mask) mask[i] = sel ? 1.0f : 0.0f;
        }
    } else {
        const unsigned int KT = lo;
        unsigned int c = 0;
#pragma unroll
        for (int j = 0; j < 20; j++) c += (key[j] > KT) ? 1u : 0u;
#pragma unroll
        for (int off = 32; off > 0; off >>= 1) c += __shfl_down(c, off, 64);
        if (lane == 0) atomicAdd(&s_cnt[35], c);
        __syncthreads();
        const int rem = K_SEL - (int)s_cnt[35];
#pragma unroll
        for (int j = 0; j < 20; j++) {
            int i = tid + j * 256;
            if (i >= N_IN) continue;
            unsigned int k = key[j];
            bool sel = false;
            if (k > KT) sel = true;
            else if (k == KT) { int t = atomicAdd(&s_tick, 1); sel = (t < rem); }
            if (sel) { int s = atomicAdd(&s_sel, 1); sidx[s] = i; }
            if (write_mask) mask[i] = sel ? 1.0f : 0.0f;
        }
    }
    __syncthreads();   // sidx complete

    // --- Phase B: gathers ---
    for (int e = tid; e < K_SEL * 32; e += 256) {
        int k = e >> 5, j = e & 31;
        sW1[e] = W1[(size_t)sidx[k] * 32 + j];   // coalesced 128B per W1 row
    }
    {
        const int r = tid >> 3;          // 0..31
        const int q = tid & 7;           // 0..7
        const int row = blockIdx.x * RPB + r;
        const float* __restrict__ xrow = x + (size_t)row * N_IN;
        float g[7];
#pragma unroll
        for (int u = 0; u < 7; u++) {
            int k = q * 7 + u;
            if (k < K_SEL) g[u] = xrow[sidx[k]];
        }
#pragma unroll
        for (int u = 0; u < 7; u++) {
            int k = q * 7 + u;
            if (k < K_SEL) xs[r * 51 + k] = g[u];
        }
    }
    __syncthreads();

    const int r = tid & 31;              // row within block
    const int c = tid >> 5;              // j-chunk, 0..7

    // --- L1: 50 -> 32, relu. 4 outputs/thread ---
    {
        float acc[4];
#pragma unroll
        for (int jj = 0; jj < 4; jj++) acc[jj] = sb1[c * 4 + jj];
        const float* xr = &xs[r * 51];
        for (int k = 0; k < K_SEL; k++) {
            float xk = xr[k];                      // stride-51: conflict-free
            const float* w = &sW1[k * 32 + c * 4]; // half-wave-uniform: broadcast
#pragma unroll
            for (int jj = 0; jj < 4; jj++) acc[jj] = fmaf(xk, w[jj], acc[jj]);
        }
#pragma unroll
        for (int jj = 0; jj < 4; jj++) h1s[r * 33 + c * 4 + jj] = fmaxf(acc[jj], 0.0f);
    }
    __syncthreads();

    // --- L2: 32 -> 16, relu. 2 outputs/thread ---
    {
        float acc[2];
#pragma unroll
        for (int jj = 0; jj < 2; jj++) acc[jj] = sb2[c * 2 + jj];
        const float* hr = &h1s[r * 33];
#pragma unroll
        for (int i = 0; i < 32; i++) {
            float a = hr[i];
            const float* w = &sW2[i * 16 + c * 2];
#pragma unroll
            for (int jj = 0; jj < 2; jj++) acc[jj] = fmaf(a, w[jj], acc[jj]);
        }
#pragma unroll
        for (int jj = 0; jj < 2; jj++) h2s[r * 17 + c * 2 + jj] = fmaxf(acc[jj], 0.0f);
    }
    __syncthreads();

    // --- L3: 16 -> 30. 4 outputs/thread (2 for c==7), staged into xs ---
    {
        const int j0 = c * 4;
        const int nj = (c == 7) ? 2 : 4;
        float acc[4];
        for (int jj = 0; jj < nj; jj++) acc[jj] = sb3[j0 + jj];
        const float* hr = &h2s[r * 17];
#pragma unroll
        for (int i = 0; i < 16; i++) {
            float a = hr[i];
            const float* w = &sW3[i * OUT_D + j0];
            for (int jj = 0; jj < nj; jj++) acc[jj] = fmaf(a, w[jj], acc[jj]);
        }
        float* so = xs;                  // reuse: 32*30 = 960 <= 32*51
        for (int jj = 0; jj < nj; jj++) so[r * OUT_D + j0 + jj] = acc[jj];
    }
    __syncthreads();

    // --- coalesced float4 epilogue: 32 rows x 30 floats = 240 float4 ---
    {
        float4* out4 = (float4*)(out + (size_t)blockIdx.x * RPB * OUT_D);
        const float4* so4 = (const float4*)xs;
        for (int e = tid; e < (RPB * OUT_D) / 4; e += 256) out4[e] = so4[e];
    }
}

extern "C" void kernel_launch(void* const* d_in, const int* in_sizes, int n_in,
                              void* d_out, int out_size, void* d_ws, size_t ws_size,
                              hipStream_t stream) {
    const float* x      = (const float*)d_in[0];
    const float* logits = (const float*)d_in[1];
    const float* W1     = (const float*)d_in[2];
    const float* b1     = (const float*)d_in[3];
    const float* W2     = (const float*)d_in[4];
    const float* b2     = (const float*)d_in[5];
    const float* W3     = (const float*)d_in[6];
    const float* b3     = (const float*)d_in[7];
    // d_in[8] = epoch, d_in[9] = total_epochs — unused on the eval path.

    float* out  = (float*)d_out;                       // [16384, 30]
    float* mask = out + (size_t)B_ROWS * OUT_D;        // [5000]

    fused_gated_mlp_kernel<<<GRID, 256, 0, stream>>>(
        x, logits, W1, b1, W2, b2, W3, b3, out, mask);
}